// Round 3
// baseline (967.211 us; speedup 1.0000x reference)
//
#include <hip/hip_runtime.h>

#define B_ 64
#define S_ 512
#define E_ 300
#define H_ 256
#define G_ 768  // 3*H

typedef _Float16 h2_t __attribute__((ext_vector_type(2)));

__device__ __forceinline__ unsigned pack_h2(float a, float b) {
  h2_t v;
  v.x = (_Float16)a;
  v.y = (_Float16)b;
  return __builtin_bit_cast(unsigned, v);
}

__device__ __forceinline__ float fdot2f(unsigned w, unsigned h, float acc) {
#if __has_builtin(__builtin_amdgcn_fdot2)
  return __builtin_amdgcn_fdot2(__builtin_bit_cast(h2_t, w),
                                __builtin_bit_cast(h2_t, h), acc, false);
#else
  h2_t wv = __builtin_bit_cast(h2_t, w), hv = __builtin_bit_cast(h2_t, h);
  return acc + (float)wv.x * (float)hv.x + (float)wv.y * (float)hv.y;
#endif
}

// ---------------------------------------------------------------------------
// Kernel 1: embedding gather + mask.  emb[b,s,e] = mask ? table[ind][e] : 0
// ---------------------------------------------------------------------------
__global__ void k_embed(const int* __restrict__ inds, const int* __restrict__ lens,
                        const float* __restrict__ table, float* __restrict__ out_emb,
                        float* __restrict__ out_mask) {
  const long total = (long)B_ * S_ * E_;
  for (long idx = (long)blockIdx.x * blockDim.x + threadIdx.x; idx < total;
       idx += (long)gridDim.x * blockDim.x) {
    int row = (int)(idx / E_);
    int e = (int)(idx - (long)row * E_);
    int b = row >> 9;
    int s = row & 511;
    bool valid = s < lens[b];
    float v = 0.0f;
    if (valid) v = table[(long)inds[row] * E_ + e];
    out_emb[idx] = v;
    if (e == 0) out_mask[row] = valid ? 1.0f : 0.0f;
  }
}

// ---------------------------------------------------------------------------
// Kernel 2: gx = emb @ w_ih^T + b_ih   [32768 x 300] x [300 x 768] -> f16
// ---------------------------------------------------------------------------
#define KC 30
__global__ __launch_bounds__(256) void k_gx(const float* __restrict__ A,
                                            const float* __restrict__ W,
                                            const float* __restrict__ bias,
                                            _Float16* __restrict__ gx) {
  __shared__ float As[KC][132];
  __shared__ float Ws[KC][132];
  const int tid = threadIdx.x;
  const int row0 = blockIdx.x * 128;
  const int col0 = blockIdx.y * 128;
  const int tx = tid & 15;
  const int ty = tid >> 4;

  float acc[8][8];
#pragma unroll
  for (int i = 0; i < 8; ++i)
#pragma unroll
    for (int j = 0; j < 8; ++j) acc[i][j] = 0.0f;

  for (int kt = 0; kt < E_ / KC; ++kt) {
    const int k0 = kt * KC;
#pragma unroll
    for (int u = 0; u < 15; ++u) {
      int idx = tid + u * 256;
      int r = idx / KC;
      int kk = idx - r * KC;
      As[kk][r] = A[(long)(row0 + r) * E_ + k0 + kk];
      Ws[kk][r] = W[(long)(col0 + r) * E_ + k0 + kk];
    }
    __syncthreads();
    for (int kk = 0; kk < KC; ++kk) {
      float4 a0 = *(const float4*)&As[kk][ty * 4];
      float4 a1 = *(const float4*)&As[kk][64 + ty * 4];
      float4 b0 = *(const float4*)&Ws[kk][tx * 4];
      float4 b1 = *(const float4*)&Ws[kk][64 + tx * 4];
      float av[8] = {a0.x, a0.y, a0.z, a0.w, a1.x, a1.y, a1.z, a1.w};
      float bv[8] = {b0.x, b0.y, b0.z, b0.w, b1.x, b1.y, b1.z, b1.w};
#pragma unroll
      for (int i = 0; i < 8; ++i)
#pragma unroll
        for (int j = 0; j < 8; ++j) acc[i][j] += av[i] * bv[j];
    }
    __syncthreads();
  }

#pragma unroll
  for (int i = 0; i < 8; ++i) {
    int r = row0 + ((i < 4) ? (ty * 4 + i) : (64 + ty * 4 + i - 4));
#pragma unroll
    for (int j = 0; j < 8; ++j) {
      int c = col0 + ((j < 4) ? (tx * 4 + j) : (64 + tx * 4 + j - 4));
      gx[(long)r * G_ + c] = (_Float16)(acc[i][j] + bias[c]);
    }
  }
}

// ---------------------------------------------------------------------------
// Kernel 3: masked GRU scan. One block per batch element, 1024 threads.
// Thread j: unit p=j>>2 (owns w_hh rows {p, H+p, 2H+p}), k-quarter q=j&3
// (k in [64q, 64q+64)). Weights: 3 gates x 32 packed half2 = 96 VGPRs —
// fits the compiler's 128-VGPR budget at 4 waves/SIMD, no spill.
// k-quarter partials combined via shfl_xor(1)+shfl_xor(2); all 4 lanes
// then compute unit p's gates (duplicated, free). h broadcast via a
// double-buffered LDS array with each quarter padded to 36 u32 (144 B,
// 16B-aligned) so quartet reads hit disjoint bank groups. One barrier/step.
// gx for step t+1 prefetched during step t.
// ---------------------------------------------------------------------------
__global__ __launch_bounds__(1024, 4) void k_gru(
    const float* __restrict__ w_hh, const float* __restrict__ b_hh,
    const int* __restrict__ lens, const _Float16* __restrict__ gx,
    float* __restrict__ feats, float* __restrict__ hid) {
  const int b = blockIdx.x;
  const int j = threadIdx.x;  // 0..1023
  const int len = lens[b];

  __shared__ unsigned h2buf[2][144];  // 4 quarters x (32 half2 + 4 pad)

  const int p = j >> 2;       // hidden unit 0..255
  const int q = j & 3;        // k-quarter
  const int qoff = 36 * q;    // padded quarter offset (u32 units)

  // load + pack weights: rows {p, H+p, 2H+p}, k-range [64q, 64q+64)
  unsigned wreg[96];
#pragma unroll
  for (int g = 0; g < 3; ++g) {
    const float* src = w_hh + ((long)g * H_ + p) * H_ + 64 * q;
#pragma unroll
    for (int c2 = 0; c2 < 16; ++c2) {
      float4 f = *(const float4*)(src + 4 * c2);
      wreg[g * 32 + 2 * c2] = pack_h2(f.x, f.y);
      wreg[g * 32 + 2 * c2 + 1] = pack_h2(f.z, f.w);
    }
  }

  const float bias_r = b_hh[p];
  const float bias_z = b_hh[H_ + p];
  const float bias_n = b_hh[2 * H_ + p];
  float hreg = 0.0f;

  if (j < 288) ((unsigned*)h2buf)[j] = 0u;  // h0 = 0 (both buffers, incl pad)
  __syncthreads();

  const _Float16* gxb = gx + (long)b * S_ * G_;
  // prefetch t=0
  float gxr = (float)gxb[p];
  float gxz = (float)gxb[H_ + p];
  float gxn = (float)gxb[2 * H_ + p];

  int cur = 0;
  for (int t = 0; t < len; ++t) {
    // issue prefetch for t+1 (latency hides under the matvec)
    const int tn = (t + 1 < len) ? (t + 1) : t;
    const _Float16* gxt = gxb + (long)tn * G_;
    _Float16 nr = gxt[p];
    _Float16 nz = gxt[H_ + p];
    _Float16 nn = gxt[2 * H_ + p];

    // ---- matvec: this thread's 3 rows over its k-quarter
    float a0 = 0.f, a1 = 0.f, a2 = 0.f;
#pragma unroll
    for (int c = 0; c < 8; ++c) {
      float4 hv = *(const float4*)&h2buf[cur][qoff + c * 4];
      unsigned h0 = __builtin_bit_cast(unsigned, hv.x);
      unsigned h1 = __builtin_bit_cast(unsigned, hv.y);
      unsigned h2v = __builtin_bit_cast(unsigned, hv.z);
      unsigned h3 = __builtin_bit_cast(unsigned, hv.w);
      a0 = fdot2f(wreg[c * 4 + 0], h0, a0);
      a0 = fdot2f(wreg[c * 4 + 1], h1, a0);
      a0 = fdot2f(wreg[c * 4 + 2], h2v, a0);
      a0 = fdot2f(wreg[c * 4 + 3], h3, a0);
      a1 = fdot2f(wreg[32 + c * 4 + 0], h0, a1);
      a1 = fdot2f(wreg[32 + c * 4 + 1], h1, a1);
      a1 = fdot2f(wreg[32 + c * 4 + 2], h2v, a1);
      a1 = fdot2f(wreg[32 + c * 4 + 3], h3, a1);
      a2 = fdot2f(wreg[64 + c * 4 + 0], h0, a2);
      a2 = fdot2f(wreg[64 + c * 4 + 1], h1, a2);
      a2 = fdot2f(wreg[64 + c * 4 + 2], h2v, a2);
      a2 = fdot2f(wreg[64 + c * 4 + 3], h3, a2);
    }
    // combine the four k-quarters (lanes 4p..4p+3); all lanes get full sums
    a0 += __shfl_xor(a0, 1);
    a0 += __shfl_xor(a0, 2);
    a1 += __shfl_xor(a1, 1);
    a1 += __shfl_xor(a1, 2);
    a2 += __shfl_xor(a2, 1);
    a2 += __shfl_xor(a2, 2);

    // ---- gates for unit p (duplicated across the quartet — free)
    float r = 1.0f / (1.0f + __expf(-(gxr + a0 + bias_r)));
    float z = 1.0f / (1.0f + __expf(-(gxz + a1 + bias_z)));
    float n = tanhf(gxn + r * (a2 + bias_n));
    hreg = (1.0f - z) * n + z * hreg;

    if (q == 0) feats[((long)b * S_ + t) * H_ + p] = hreg;

    // repack h: lane 8i has h[2i], lane 8i+4 has h[2i+1]
    float hother = __shfl_xor(hreg, 4);
    if ((j & 7) == 0) {
      int i = j >> 3;  // half2 index 0..127
      h2buf[cur ^ 1][36 * (i >> 5) + (i & 31)] = pack_h2(hreg, hother);
    }

    __syncthreads();
    cur ^= 1;
    gxr = (float)nr;
    gxz = (float)nz;
    gxn = (float)nn;
  }

  // zero feats past len (reference masks them to 0)
  {
    const long tail = (long)(S_ - len) * H_;
    float* dst = feats + ((long)b * S_ + len) * H_;
    for (long idx = j; idx < tail; idx += 1024) dst[idx] = 0.0f;
  }
  if (q == 0) hid[b * H_ + p] = hreg;
}

// ---------------------------------------------------------------------------
extern "C" void kernel_launch(void* const* d_in, const int* in_sizes, int n_in,
                              void* d_out, int out_size, void* d_ws, size_t ws_size,
                              hipStream_t stream) {
  const int* inds = (const int*)d_in[0];
  const int* lens = (const int*)d_in[1];
  const float* table = (const float*)d_in[2];
  const float* w_ih = (const float*)d_in[3];
  const float* w_hh = (const float*)d_in[4];
  const float* b_ih = (const float*)d_in[5];
  const float* b_hh = (const float*)d_in[6];

  float* out = (float*)d_out;
  float* out_emb = out;                              // B*S*E
  float* out_feats = out + (long)B_ * S_ * E_;       // B*S*H
  float* out_mask = out_feats + (long)B_ * S_ * H_;  // B*S
  float* out_hid = out_mask + (long)B_ * S_;         // B*H

  _Float16* gx = (_Float16*)d_ws;  // B*S*3H f16

  k_embed<<<2048, 256, 0, stream>>>(inds, lens, table, out_emb, out_mask);
  dim3 g2(32768 / 128, G_ / 128);
  k_gx<<<g2, 256, 0, stream>>>(out_emb, w_ih, b_ih, gx);
  k_gru<<<B_, 1024, 0, stream>>>(w_hh, b_hh, lens, gx, out_feats, out_hid);
}

// Round 4
// 774.891 us; speedup vs baseline: 1.2482x; 1.2482x over previous
//
#include <hip/hip_runtime.h>

#define B_ 64
#define S_ 512
#define E_ 300
#define H_ 256
#define G_ 768  // 3*H

typedef _Float16 h2_t __attribute__((ext_vector_type(2)));
typedef unsigned u32x16 __attribute__((ext_vector_type(16)));

__device__ __forceinline__ unsigned pack_h2(float a, float b) {
  h2_t v;
  v.x = (_Float16)a;
  v.y = (_Float16)b;
  return __builtin_bit_cast(unsigned, v);
}

__device__ __forceinline__ float fdot2f(unsigned w, unsigned h, float acc) {
  return __builtin_amdgcn_fdot2(__builtin_bit_cast(h2_t, w),
                                __builtin_bit_cast(h2_t, h), acc, false);
}

// pack 32 consecutive floats into 16 half2 lanes of a u32x16 (pure SSA —
// ext_vector insertelement, never an alloca, so it CANNOT go to scratch)
__device__ __forceinline__ u32x16 load_pack32(const float* __restrict__ src) {
  u32x16 d;
#pragma unroll
  for (int e = 0; e < 8; ++e) {
    float4 f = *(const float4*)(src + 4 * e);
    d[2 * e] = pack_h2(f.x, f.y);
    d[2 * e + 1] = pack_h2(f.z, f.w);
  }
  return d;
}

__device__ __forceinline__ float fast_sigmoid(float x) {
  return __builtin_amdgcn_rcpf(1.0f + __builtin_amdgcn_exp2f(-1.44269504f * x));
}
__device__ __forceinline__ float fast_tanh(float x) {
  float e = __builtin_amdgcn_exp2f(-2.88539008f * fabsf(x));
  return copysignf((1.0f - e) * __builtin_amdgcn_rcpf(1.0f + e), x);
}

// ---------------------------------------------------------------------------
// Kernel 1: embedding gather + mask.
// ---------------------------------------------------------------------------
__global__ void k_embed(const int* __restrict__ inds, const int* __restrict__ lens,
                        const float* __restrict__ table, float* __restrict__ out_emb,
                        float* __restrict__ out_mask) {
  const long total = (long)B_ * S_ * E_;
  for (long idx = (long)blockIdx.x * blockDim.x + threadIdx.x; idx < total;
       idx += (long)gridDim.x * blockDim.x) {
    int row = (int)(idx / E_);
    int e = (int)(idx - (long)row * E_);
    int b = row >> 9;
    int s = row & 511;
    bool valid = s < lens[b];
    float v = 0.0f;
    if (valid) v = table[(long)inds[row] * E_ + e];
    out_emb[idx] = v;
    if (e == 0) out_mask[row] = valid ? 1.0f : 0.0f;
  }
}

// ---------------------------------------------------------------------------
// Kernel 2: gx = emb @ w_ih^T + b_ih   [32768 x 300] x [300 x 768] -> f16
// ---------------------------------------------------------------------------
#define KC 30
__global__ __launch_bounds__(256) void k_gx(const float* __restrict__ A,
                                            const float* __restrict__ W,
                                            const float* __restrict__ bias,
                                            _Float16* __restrict__ gx) {
  __shared__ float As[KC][132];
  __shared__ float Ws[KC][132];
  const int tid = threadIdx.x;
  const int row0 = blockIdx.x * 128;
  const int col0 = blockIdx.y * 128;
  const int tx = tid & 15;
  const int ty = tid >> 4;

  float acc[8][8];
#pragma unroll
  for (int i = 0; i < 8; ++i)
#pragma unroll
    for (int j = 0; j < 8; ++j) acc[i][j] = 0.0f;

  for (int kt = 0; kt < E_ / KC; ++kt) {
    const int k0 = kt * KC;
#pragma unroll
    for (int u = 0; u < 15; ++u) {
      int idx = tid + u * 256;
      int r = idx / KC;
      int kk = idx - r * KC;
      As[kk][r] = A[(long)(row0 + r) * E_ + k0 + kk];
      Ws[kk][r] = W[(long)(col0 + r) * E_ + k0 + kk];
    }
    __syncthreads();
    for (int kk = 0; kk < KC; ++kk) {
      float4 a0 = *(const float4*)&As[kk][ty * 4];
      float4 a1 = *(const float4*)&As[kk][64 + ty * 4];
      float4 b0 = *(const float4*)&Ws[kk][tx * 4];
      float4 b1 = *(const float4*)&Ws[kk][64 + tx * 4];
      float av[8] = {a0.x, a0.y, a0.z, a0.w, a1.x, a1.y, a1.z, a1.w};
      float bv[8] = {b0.x, b0.y, b0.z, b0.w, b1.x, b1.y, b1.z, b1.w};
#pragma unroll
      for (int i = 0; i < 8; ++i)
#pragma unroll
        for (int j = 0; j < 8; ++j) acc[i][j] += av[i] * bv[j];
    }
    __syncthreads();
  }

#pragma unroll
  for (int i = 0; i < 8; ++i) {
    int r = row0 + ((i < 4) ? (ty * 4 + i) : (64 + ty * 4 + i - 4));
#pragma unroll
    for (int j = 0; j < 8; ++j) {
      int c = col0 + ((j < 4) ? (tx * 4 + j) : (64 + tx * 4 + j - 4));
      gx[(long)r * G_ + c] = (_Float16)(acc[i][j] + bias[c]);
    }
  }
}

// ---------------------------------------------------------------------------
// Kernel 3: masked GRU scan. 64 blocks x 512 threads, 2 waves/SIMD.
// Thread j (p=j>>1, hf=j&1): w_hh rows {p, H+p, 2H+p}, k in [128hf,128hf+128),
// held as 12 u32x16 SSA vectors (192 half2 = 192 VGPRs, spill-proof).
// k-half partials combined with shfl_xor(1); both lanes compute the gates.
// h broadcast via double-buffered 128-half2 LDS; ONE barrier per step.
// ---------------------------------------------------------------------------
__attribute__((amdgpu_waves_per_eu(1, 2))) __global__ void
__launch_bounds__(512) k_gru(const float* __restrict__ w_hh,
                             const float* __restrict__ b_hh,
                             const int* __restrict__ lens,
                             const _Float16* __restrict__ gx,
                             float* __restrict__ feats, float* __restrict__ hid) {
  const int b = blockIdx.x;
  const int j = threadIdx.x;  // 0..511
  const int len = lens[b];

  __shared__ __align__(16) unsigned h2buf[2][128];

  const int p = j >> 1;      // hidden unit 0..255
  const int hf = j & 1;      // k-half
  const int hf64 = hf * 64;  // half2 offset of this k-half

  const float* s_r = w_hh + (long)p * H_ + 128 * hf;
  const float* s_z = w_hh + ((long)H_ + p) * H_ + 128 * hf;
  const float* s_n = w_hh + ((long)2 * H_ + p) * H_ + 128 * hf;

  u32x16 wr0 = load_pack32(s_r + 0), wr1 = load_pack32(s_r + 32),
         wr2 = load_pack32(s_r + 64), wr3 = load_pack32(s_r + 96);
  u32x16 wz0 = load_pack32(s_z + 0), wz1 = load_pack32(s_z + 32),
         wz2 = load_pack32(s_z + 64), wz3 = load_pack32(s_z + 96);
  u32x16 wn0 = load_pack32(s_n + 0), wn1 = load_pack32(s_n + 32),
         wn2 = load_pack32(s_n + 64), wn3 = load_pack32(s_n + 96);

  const float bias_r = b_hh[p];
  const float bias_z = b_hh[H_ + p];
  const float bias_n = b_hh[2 * H_ + p];
  float hreg = 0.0f;

  if (j < 128) h2buf[0][j] = 0u;  // h0 = 0
  __syncthreads();

  const _Float16* gxb = gx + (long)b * S_ * G_;
  float gxr = (float)gxb[p];
  float gxz = (float)gxb[H_ + p];
  float gxn = (float)gxb[2 * H_ + p];

  int cur = 0;
  for (int t = 0; t < len; ++t) {
    const int tn = (t + 1 < len) ? (t + 1) : t;
    const _Float16* gxt = gxb + (long)tn * G_;
    _Float16 nr = gxt[p];
    _Float16 nz = gxt[H_ + p];
    _Float16 nn = gxt[2 * H_ + p];

    float a0 = 0.f, a1 = 0.f, a2 = 0.f;

// CC is a literal 0..15; vector element indices fold to constants.
#define DOTQ(WR, WZ, WN, CC)                                        \
  do {                                                              \
    float4 hv = *(const float4*)&h2buf[cur][hf64 + 4 * (CC)];       \
    unsigned hq0 = __builtin_bit_cast(unsigned, hv.x);              \
    unsigned hq1 = __builtin_bit_cast(unsigned, hv.y);              \
    unsigned hq2 = __builtin_bit_cast(unsigned, hv.z);              \
    unsigned hq3 = __builtin_bit_cast(unsigned, hv.w);              \
    a0 = fdot2f(WR[4 * ((CC)&3) + 0], hq0, a0);                     \
    a0 = fdot2f(WR[4 * ((CC)&3) + 1], hq1, a0);                     \
    a0 = fdot2f(WR[4 * ((CC)&3) + 2], hq2, a0);                     \
    a0 = fdot2f(WR[4 * ((CC)&3) + 3], hq3, a0);                     \
    a1 = fdot2f(WZ[4 * ((CC)&3) + 0], hq0, a1);                     \
    a1 = fdot2f(WZ[4 * ((CC)&3) + 1], hq1, a1);                     \
    a1 = fdot2f(WZ[4 * ((CC)&3) + 2], hq2, a1);                     \
    a1 = fdot2f(WZ[4 * ((CC)&3) + 3], hq3, a1);                     \
    a2 = fdot2f(WN[4 * ((CC)&3) + 0], hq0, a2);                     \
    a2 = fdot2f(WN[4 * ((CC)&3) + 1], hq1, a2);                     \
    a2 = fdot2f(WN[4 * ((CC)&3) + 2], hq2, a2);                     \
    a2 = fdot2f(WN[4 * ((CC)&3) + 3], hq3, a2);                     \
  } while (0)

    DOTQ(wr0, wz0, wn0, 0);
    DOTQ(wr0, wz0, wn0, 1);
    DOTQ(wr0, wz0, wn0, 2);
    DOTQ(wr0, wz0, wn0, 3);
    DOTQ(wr1, wz1, wn1, 4);
    DOTQ(wr1, wz1, wn1, 5);
    DOTQ(wr1, wz1, wn1, 6);
    DOTQ(wr1, wz1, wn1, 7);
    DOTQ(wr2, wz2, wn2, 8);
    DOTQ(wr2, wz2, wn2, 9);
    DOTQ(wr2, wz2, wn2, 10);
    DOTQ(wr2, wz2, wn2, 11);
    DOTQ(wr3, wz3, wn3, 12);
    DOTQ(wr3, wz3, wn3, 13);
    DOTQ(wr3, wz3, wn3, 14);
    DOTQ(wr3, wz3, wn3, 15);
#undef DOTQ

    // combine the two k-halves (lanes j, j^1); both lanes get full sums
    a0 += __shfl_xor(a0, 1);
    a1 += __shfl_xor(a1, 1);
    a2 += __shfl_xor(a2, 1);

    // gates for unit p (duplicated across the pair — free)
    float r = fast_sigmoid(gxr + a0 + bias_r);
    float z = fast_sigmoid(gxz + a1 + bias_z);
    float n = fast_tanh(gxn + r * (a2 + bias_n));
    hreg = (1.0f - z) * n + z * hreg;

    if (hf == 0) feats[((long)b * S_ + t) * H_ + p] = hreg;

    // pack h into the other buffer: lane 4i holds h[2i], lane 4i+2 h[2i+1]
    float hother = __shfl_xor(hreg, 2);
    if ((j & 3) == 0) h2buf[cur ^ 1][j >> 2] = pack_h2(hreg, hother);

    __syncthreads();
    cur ^= 1;
    gxr = (float)nr;
    gxz = (float)nz;
    gxn = (float)nn;
  }

  // zero feats past len (reference masks them to 0)
  {
    const long tail = (long)(S_ - len) * H_;
    float* dst = feats + ((long)b * S_ + len) * H_;
    for (long idx = j; idx < tail; idx += 512) dst[idx] = 0.0f;
  }
  if (hf == 0) hid[b * H_ + p] = hreg;
}

// ---------------------------------------------------------------------------
extern "C" void kernel_launch(void* const* d_in, const int* in_sizes, int n_in,
                              void* d_out, int out_size, void* d_ws, size_t ws_size,
                              hipStream_t stream) {
  const int* inds = (const int*)d_in[0];
  const int* lens = (const int*)d_in[1];
  const float* table = (const float*)d_in[2];
  const float* w_ih = (const float*)d_in[3];
  const float* w_hh = (const float*)d_in[4];
  const float* b_ih = (const float*)d_in[5];
  const float* b_hh = (const float*)d_in[6];

  float* out = (float*)d_out;
  float* out_emb = out;                              // B*S*E
  float* out_feats = out + (long)B_ * S_ * E_;       // B*S*H
  float* out_mask = out_feats + (long)B_ * S_ * H_;  // B*S
  float* out_hid = out_mask + (long)B_ * S_;         // B*H

  _Float16* gx = (_Float16*)d_ws;  // B*S*3H f16

  k_embed<<<2048, 256, 0, stream>>>(inds, lens, table, out_emb, out_mask);
  dim3 g2(32768 / 128, G_ / 128);
  k_gx<<<g2, 256, 0, stream>>>(out_emb, w_ih, b_ih, gx);
  k_gru<<<B_, 512, 0, stream>>>(w_hh, b_hh, lens, gx, out_feats, out_hid);
}